// Round 5
// baseline (356.929 us; speedup 1.0000x reference)
//
#include <hip/hip_runtime.h>
#include <hip/hip_bf16.h>

#define IN_F 128
#define HID 16
#define OUT_F 64
#define XT_LD 132   // padded LDS stride for x tile in k_xw1
#define BINW 512    // nodes per bin (dst >> 9)
#define BSH 9
#define MAXNB 256   // supports n <= 131072
#define EPT 16      // edges per thread in bincount
#define EPTS 32     // edges per thread in scatter (longer spans -> fewer partial lines)

// ---------- dtype-flex helpers (device-side runtime dtype detection) ----------
__device__ __forceinline__ float loadF(const void* p, size_t i, int bf) {
  if (bf) {
    unsigned v = ((unsigned)((const unsigned short*)p)[i]) << 16;
    float f; __builtin_memcpy(&f, &v, 4); return f;
  }
  return ((const float*)p)[i];
}
__device__ __forceinline__ int loadE_nt(const void* p, size_t i, int i64) {
  if (i64) return __builtin_nontemporal_load((const int*)p + 2 * i);  // little-endian low word
  return __builtin_nontemporal_load((const int*)p + i);
}

// flags[0] = 1 if float tensors are bf16; flags[1] = 1 if edge_index is int64
__global__ void k_detect(const void* x, const void* ei, int* flags) {
  __shared__ int c_ok, c_hi;
  int t = threadIdx.x;
  if (t == 0) { c_ok = 0; c_hi = 0; }
  __syncthreads();
  const float* xf = (const float*)x;
  int ok = 0;
  for (int i = t; i < 1024; i += 256) {
    float v = fabsf(xf[i]);
    if (v > 1e-4f && v < 1e4f) ok++;   // N(0,1) f32 passes ~always; packed bf16 ~never
  }
  const int* ep = (const int*)ei;
  int hi = 0;
  for (int i = t; i < 1024; i += 256)
    if (ep[2 * i + 1] != 0) hi++;      // int64 ids < 2^31 -> high words all zero
  atomicAdd(&c_ok, ok);
  atomicAdd(&c_hi, hi);
  __syncthreads();
  if (t == 0) {
    flags[0] = (c_ok < 512) ? 1 : 0;
    flags[1] = (c_hi == 0) ? 1 : 0;
  }
}

// ---------- pass 1: per-bin edge counts (LDS histogram, few global atomics) ----------
__global__ __launch_bounds__(256) void k_bincount(const void* ei, const int* flags,
                                                  unsigned* gcnt, int e, int nb) {
  __shared__ unsigned hist[MAXNB];
  const int t = threadIdx.x;
  for (int i = t; i < nb; i += 256) hist[i] = 0;
  __syncthreads();
  const int i64 = flags[1];
  const size_t base = (size_t)blockIdx.x * (256 * EPT);
  #pragma unroll
  for (int j = 0; j < EPT; ++j) {
    size_t idx = base + (size_t)j * 256 + t;
    if (idx < (size_t)e) {
      int d = loadE_nt(ei, (size_t)e + idx, i64);
      atomicAdd(&hist[d >> BSH], 1u);
    }
  }
  __syncthreads();
  for (int i = t; i < nb; i += 256)
    if (hist[i]) atomicAdd(&gcnt[i], hist[i]);
}

// ---------- exclusive scan over nb (<=1024) bin counts; also primes gcur ----------
__global__ __launch_bounds__(256) void k_scan(const unsigned* gcnt, unsigned* offs,
                                              unsigned* gcur, int nb) {
  __shared__ unsigned s[256];
  const int t = threadIdx.x;
  unsigned c[4]; unsigned sum = 0;
  #pragma unroll
  for (int j = 0; j < 4; ++j) {
    int i = t * 4 + j;
    c[j] = (i < nb) ? gcnt[i] : 0u;
    sum += c[j];
  }
  s[t] = sum; __syncthreads();
  for (int d = 1; d < 256; d <<= 1) {
    unsigned a = (t >= d) ? s[t - d] : 0u;
    __syncthreads();
    s[t] += a;
    __syncthreads();
  }
  unsigned run = s[t] - sum;   // exclusive prefix of this thread's chunk
  #pragma unroll
  for (int j = 0; j < 4; ++j) {
    int i = t * 4 + j;
    if (i < nb) { offs[i] = run; gcur[i] = run; run += c[j]; }
  }
}

// ---------- pass 2: scatter edges into bins (wg-bulk reservation -> long spans) ----------
__global__ __launch_bounds__(256) void k_scatter(const void* ei, const int* flags,
                                                 unsigned* gcur, unsigned* binbuf,
                                                 int e, int nb) {
  __shared__ unsigned hist[MAXNB];
  __shared__ unsigned rbase[MAXNB];
  const int t = threadIdx.x;
  for (int i = t; i < nb; i += 256) hist[i] = 0;
  __syncthreads();
  const int i64 = flags[1];
  const size_t base = (size_t)blockIdx.x * (256 * EPTS);
  unsigned pk[EPTS]; int bn[EPTS];
  #pragma unroll
  for (int j = 0; j < EPTS; ++j) {
    size_t idx = base + (size_t)j * 256 + t;
    if (idx < (size_t)e) {
      int s = loadE_nt(ei, idx, i64);
      int d = loadE_nt(ei, (size_t)e + idx, i64);
      bn[j] = d >> BSH;
      pk[j] = (unsigned)s | ((unsigned)(d & (BINW - 1)) << 17);
      atomicAdd(&hist[bn[j]], 1u);
    } else bn[j] = -1;
  }
  __syncthreads();
  for (int i = t; i < nb; i += 256) {
    unsigned h = hist[i];
    rbase[i] = h ? atomicAdd(&gcur[i], h) : 0u;
    hist[i] = 0;                       // reuse as per-wg cursor
  }
  __syncthreads();
  #pragma unroll
  for (int j = 0; j < EPTS; ++j)
    if (bn[j] >= 0) {
      unsigned p = rbase[bn[j]] + atomicAdd(&hist[bn[j]], 1u);
      __builtin_nontemporal_store(pk[j], binbuf + p);
    }
}

// ---------- pass 3: within-bin counting sort by local dst -> per-node CSR ----------
// Writes land in a 64KB window per wg -> L2 write-combines -> streaming traffic.
__global__ __launch_bounds__(512) void k_sort(const unsigned* binbuf, const unsigned* offs,
                                              const unsigned* gcnt, unsigned* csr,
                                              unsigned* offs2, float* dinv, int n, int e) {
  __shared__ unsigned hist[BINW];
  __shared__ unsigned scn[BINW];
  __shared__ unsigned cur[BINW];
  const int b = blockIdx.x, t = threadIdx.x;
  hist[t] = 0;
  __syncthreads();
  const unsigned off = offs[b], cnt = gcnt[b];
  for (unsigned i = t; i < cnt; i += 512)
    atomicAdd(&hist[binbuf[off + i] >> 17], 1u);
  __syncthreads();
  scn[t] = hist[t];
  __syncthreads();
  for (int d = 1; d < BINW; d <<= 1) {
    unsigned a = (t >= d) ? scn[t - d] : 0u;
    __syncthreads();
    scn[t] += a;
    __syncthreads();
  }
  {
    unsigned excl = scn[t] - hist[t];
    cur[t] = excl;
    int g = b * BINW + t;
    if (g < n) {
      offs2[g] = off + excl;
      dinv[g] = rsqrtf((float)(hist[t] + 1u));   // +1 self-loop
    }
  }
  if (b == 0 && t == 0) offs2[n] = (unsigned)e;  // sentinel
  __syncthreads();
  for (unsigned i = t; i < cnt; i += 512) {
    unsigned pk = binbuf[off + i];
    unsigned dl = pk >> 17;
    unsigned p = atomicAdd(&cur[dl], 1u);
    csr[off + p] = pk & 0x1FFFFu;
  }
}

// ---------- hs1 = dinv[n] * (x @ W1) ----------
__global__ __launch_bounds__(256) void k_xw1(const void* x, const void* W1,
                                             const int* flags, const float* dinv,
                                             float* hs1, int n) {
  __shared__ float w[IN_F * HID];
  __shared__ float xt[16 * XT_LD];
  const int t = threadIdx.x;
  const int bf = flags[0];
  for (int i = t; i < IN_F * HID; i += 256) w[i] = loadF(W1, i, bf);
  const int n0 = blockIdx.x * 16;
  for (int i = t; i < 16 * IN_F; i += 256) {
    int rl = i >> 7, k = i & 127;
    int row = n0 + rl;
    xt[rl * XT_LD + k] = (row < n) ? loadF(x, (size_t)row * IN_F + k, bf) : 0.f;
  }
  __syncthreads();
  const int ln = t >> 4, c = t & 15;
  const int node = n0 + ln;
  if (node >= n) return;
  float acc = 0.f;
  #pragma unroll 16
  for (int k = 0; k < IN_F; ++k)
    acc = fmaf(xt[ln * XT_LD + k], w[k * HID + c], acc);
  hs1[(size_t)node * HID + c] = dinv[node] * acc;
}

// ---------- layer-1 aggregation: wave-per-node gather + register accumulate ----------
__global__ __launch_bounds__(256) void k_agg1(const unsigned* csr, const unsigned* offs2,
                                              const float* dinv, const float* hs1,
                                              const void* b1, const int* flags,
                                              float* hd, int n) {
  const int wid = (blockIdx.x * 256 + threadIdx.x) >> 6;
  if (wid >= n) return;
  const int lane = threadIdx.x & 63;
  const int sub = lane >> 2, ch = lane & 3;
  const unsigned off = offs2[wid];
  const unsigned cnt = offs2[wid + 1] - off;
  float4 acc = make_float4(0.f, 0.f, 0.f, 0.f);
  for (unsigned i = sub; i < cnt; i += 16) {
    unsigned s = __builtin_nontemporal_load(csr + off + i);
    const float4 v = ((const float4*)(hs1 + (size_t)s * HID))[ch];
    acc.x += v.x; acc.y += v.y; acc.z += v.z; acc.w += v.w;
  }
  #pragma unroll
  for (int m = 4; m < 64; m <<= 1) {
    acc.x += __shfl_xor(acc.x, m, 64);
    acc.y += __shfl_xor(acc.y, m, 64);
    acc.z += __shfl_xor(acc.z, m, 64);
    acc.w += __shfl_xor(acc.w, m, 64);
  }
  if (lane < 4) {
    const float di = dinv[wid];
    const float4 sv = ((const float4*)(hs1 + (size_t)wid * HID))[ch];
    const int bf = flags[0];
    float4 o;
    o.x = di * fmaxf(fmaf(di, acc.x + sv.x, loadF(b1, ch * 4 + 0, bf)), 0.f);
    o.y = di * fmaxf(fmaf(di, acc.y + sv.y, loadF(b1, ch * 4 + 1, bf)), 0.f);
    o.z = di * fmaxf(fmaf(di, acc.z + sv.z, loadF(b1, ch * 4 + 2, bf)), 0.f);
    o.w = di * fmaxf(fmaf(di, acc.w + sv.w, loadF(b1, ch * 4 + 3, bf)), 0.f);
    ((float4*)(hd + (size_t)wid * HID))[ch] = o;
  }
}

// ---------- layer-2 aggregation + fused 16->64 transform + relu ----------
__global__ __launch_bounds__(256) void k_agg2(const unsigned* csr, const unsigned* offs2,
                                              const float* dinv, const float* hd,
                                              const void* W2, const void* b2,
                                              const int* flags, void* out, int n) {
  __shared__ float w2s[HID * OUT_F];
  const int t = threadIdx.x;
  const int bf = flags[0];
  for (int i = t; i < HID * OUT_F; i += 256) w2s[i] = loadF(W2, i, bf);
  __syncthreads();
  const int wid = (blockIdx.x * 256 + t) >> 6;
  if (wid >= n) return;
  const int lane = t & 63;
  const int sub = lane >> 2, ch = lane & 3;
  const unsigned off = offs2[wid];
  const unsigned cnt = offs2[wid + 1] - off;
  float4 acc = make_float4(0.f, 0.f, 0.f, 0.f);
  for (unsigned i = sub; i < cnt; i += 16) {
    unsigned s = __builtin_nontemporal_load(csr + off + i);
    const float4 v = ((const float4*)(hd + (size_t)s * HID))[ch];
    acc.x += v.x; acc.y += v.y; acc.z += v.z; acc.w += v.w;
  }
  #pragma unroll
  for (int m = 4; m < 64; m <<= 1) {
    acc.x += __shfl_xor(acc.x, m, 64);
    acc.y += __shfl_xor(acc.y, m, 64);
    acc.z += __shfl_xor(acc.z, m, 64);
    acc.w += __shfl_xor(acc.w, m, 64);
  }
  const float di = dinv[wid];
  const float4 sv = ((const float4*)(hd + (size_t)wid * HID))[ch];
  acc.x = di * (acc.x + sv.x);
  acc.y = di * (acc.y + sv.y);
  acc.z = di * (acc.z + sv.z);
  acc.w = di * (acc.w + sv.w);
  float a[16];
  #pragma unroll
  for (int j = 0; j < 4; ++j) {
    a[4 * j + 0] = __shfl(acc.x, j, 64);
    a[4 * j + 1] = __shfl(acc.y, j, 64);
    a[4 * j + 2] = __shfl(acc.z, j, 64);
    a[4 * j + 3] = __shfl(acc.w, j, 64);
  }
  float o = loadF(b2, lane, bf);
  #pragma unroll
  for (int k = 0; k < HID; ++k) o = fmaf(a[k], w2s[k * OUT_F + lane], o);
  o = fmaxf(o, 0.f);
  size_t oi = (size_t)wid * OUT_F + lane;
  if (bf) ((__hip_bfloat16*)out)[oi] = __float2bfloat16(o);
  else    ((float*)out)[oi] = o;
}

extern "C" void kernel_launch(void* const* d_in, const int* in_sizes, int n_in,
                              void* d_out, int out_size, void* d_ws, size_t ws_size,
                              hipStream_t stream) {
  const void* x  = d_in[0];
  const void* ei = d_in[1];
  const void* W1 = d_in[2];
  const void* b1 = d_in[3];
  const void* W2 = d_in[4];
  const void* b2 = d_in[5];
  const int n = in_sizes[0] / IN_F;
  const int e = in_sizes[1] / 2;
  const int nb = (n + BINW - 1) / BINW;

  char* p = (char*)d_ws;
  auto alloc = [&](size_t bytes) -> char* {
    char* r = p;
    p += (bytes + 255) & ~(size_t)255;
    return r;
  };
  int*      flags  = (int*)alloc(256);
  unsigned* gcnt   = (unsigned*)alloc(MAXNB * 4);
  unsigned* offs   = (unsigned*)alloc(MAXNB * 4);
  unsigned* gcur   = (unsigned*)alloc(MAXNB * 4);
  float*    dinv   = (float*)alloc((size_t)n * 4);
  unsigned* offs2  = (unsigned*)alloc(((size_t)n + 1) * 4);
  float*    hs1    = (float*)alloc((size_t)n * HID * 4);
  float*    hd     = (float*)alloc((size_t)n * HID * 4);
  unsigned* binbuf = (unsigned*)alloc((size_t)e * 4);
  unsigned* csr    = (unsigned*)alloc((size_t)e * 4);

  const int nbE  = (e + 256 * EPT  - 1) / (256 * EPT);
  const int nbES = (e + 256 * EPTS - 1) / (256 * EPTS);

  k_detect<<<1, 256, 0, stream>>>(x, ei, flags);
  hipMemsetAsync(gcnt, 0, MAXNB * 4, stream);
  k_bincount<<<nbE, 256, 0, stream>>>(ei, flags, gcnt, e, nb);
  k_scan<<<1, 256, 0, stream>>>(gcnt, offs, gcur, nb);
  k_scatter<<<nbES, 256, 0, stream>>>(ei, flags, gcur, binbuf, e, nb);
  k_sort<<<nb, 512, 0, stream>>>(binbuf, offs, gcnt, csr, offs2, dinv, n, e);
  k_xw1<<<(n + 15) / 16, 256, 0, stream>>>(x, W1, flags, dinv, hs1, n);
  k_agg1<<<(n + 3) / 4, 256, 0, stream>>>(csr, offs2, dinv, hs1, b1, flags, hd, n);
  k_agg2<<<(n + 3) / 4, 256, 0, stream>>>(csr, offs2, dinv, hd, W2, b2, flags, d_out, n);
}

// Round 6
// 347.479 us; speedup vs baseline: 1.0272x; 1.0272x over previous
//
#include <hip/hip_runtime.h>
#include <hip/hip_bf16.h>

#define IN_F 128
#define HID 16
#define OUT_F 64
#define XT_LD 132   // padded LDS stride for x tile in k_xw1
#define BINW 512    // nodes per bin (dst >> 9)
#define BSH 9
#define MAXNB 256   // supports n <= 131072
#define EPT 16      // edges per thread in bincount
#define EPTS 32     // edges per thread in scatter

// ---------- dtype-flex helpers (device-side runtime dtype detection) ----------
__device__ __forceinline__ float loadF(const void* p, size_t i, int bf) {
  if (bf) {
    unsigned v = ((unsigned)((const unsigned short*)p)[i]) << 16;
    float f; __builtin_memcpy(&f, &v, 4); return f;
  }
  return ((const float*)p)[i];
}
__device__ __forceinline__ int loadE_nt(const void* p, size_t i, int i64) {
  if (i64) return __builtin_nontemporal_load((const int*)p + 2 * i);  // little-endian low word
  return __builtin_nontemporal_load((const int*)p + i);
}

// flags[0] = 1 if float tensors are bf16; flags[1] = 1 if edge_index is int64
__global__ void k_detect(const void* x, const void* ei, int* flags) {
  __shared__ int c_ok, c_hi;
  int t = threadIdx.x;
  if (t == 0) { c_ok = 0; c_hi = 0; }
  __syncthreads();
  const float* xf = (const float*)x;
  int ok = 0;
  for (int i = t; i < 1024; i += 256) {
    float v = fabsf(xf[i]);
    if (v > 1e-4f && v < 1e4f) ok++;   // N(0,1) f32 passes ~always; packed bf16 ~never
  }
  const int* ep = (const int*)ei;
  int hi = 0;
  for (int i = t; i < 1024; i += 256)
    if (ep[2 * i + 1] != 0) hi++;      // int64 ids < 2^31 -> high words all zero
  atomicAdd(&c_ok, ok);
  atomicAdd(&c_hi, hi);
  __syncthreads();
  if (t == 0) {
    flags[0] = (c_ok < 512) ? 1 : 0;
    flags[1] = (c_hi == 0) ? 1 : 0;
  }
}

// ---------- pass 1: per-bin edge counts (LDS histogram, few global atomics) ----------
__global__ __launch_bounds__(256) void k_bincount(const void* ei, const int* flags,
                                                  unsigned* gcnt, int e, int nb) {
  __shared__ unsigned hist[MAXNB];
  const int t = threadIdx.x;
  for (int i = t; i < nb; i += 256) hist[i] = 0;
  __syncthreads();
  const int i64 = flags[1];
  const size_t base = (size_t)blockIdx.x * (256 * EPT);
  #pragma unroll
  for (int j = 0; j < EPT; ++j) {
    size_t idx = base + (size_t)j * 256 + t;
    if (idx < (size_t)e) {
      int d = loadE_nt(ei, (size_t)e + idx, i64);
      atomicAdd(&hist[d >> BSH], 1u);
    }
  }
  __syncthreads();
  for (int i = t; i < nb; i += 256)
    if (hist[i]) atomicAdd(&gcnt[i], hist[i]);
}

// ---------- exclusive scan over nb (<=1024) bin counts; also primes gcur ----------
__global__ __launch_bounds__(256) void k_scan(const unsigned* gcnt, unsigned* offs,
                                              unsigned* gcur, int nb) {
  __shared__ unsigned s[256];
  const int t = threadIdx.x;
  unsigned c[4]; unsigned sum = 0;
  #pragma unroll
  for (int j = 0; j < 4; ++j) {
    int i = t * 4 + j;
    c[j] = (i < nb) ? gcnt[i] : 0u;
    sum += c[j];
  }
  s[t] = sum; __syncthreads();
  for (int d = 1; d < 256; d <<= 1) {
    unsigned a = (t >= d) ? s[t - d] : 0u;
    __syncthreads();
    s[t] += a;
    __syncthreads();
  }
  unsigned run = s[t] - sum;   // exclusive prefix of this thread's chunk
  #pragma unroll
  for (int j = 0; j < 4; ++j) {
    int i = t * 4 + j;
    if (i < nb) { offs[i] = run; gcur[i] = run; run += c[j]; }
  }
}

// ---------- pass 2: scatter edges into bins (wg-bulk reservation; PLAIN stores so
// L2 write-combines the spans — NT stores caused ~9x write amplification) ----------
__global__ __launch_bounds__(256) void k_scatter(const void* ei, const int* flags,
                                                 unsigned* gcur, unsigned* binbuf,
                                                 int e, int nb) {
  __shared__ unsigned hist[MAXNB];
  __shared__ unsigned rbase[MAXNB];
  const int t = threadIdx.x;
  for (int i = t; i < nb; i += 256) hist[i] = 0;
  __syncthreads();
  const int i64 = flags[1];
  const size_t base = (size_t)blockIdx.x * (256 * EPTS);
  unsigned pk[EPTS]; int bn[EPTS];
  #pragma unroll
  for (int j = 0; j < EPTS; ++j) {
    size_t idx = base + (size_t)j * 256 + t;
    if (idx < (size_t)e) {
      int s = loadE_nt(ei, idx, i64);
      int d = loadE_nt(ei, (size_t)e + idx, i64);
      bn[j] = d >> BSH;
      pk[j] = (unsigned)s | ((unsigned)(d & (BINW - 1)) << 17);
      atomicAdd(&hist[bn[j]], 1u);
    } else bn[j] = -1;
  }
  __syncthreads();
  for (int i = t; i < nb; i += 256) {
    unsigned h = hist[i];
    rbase[i] = h ? atomicAdd(&gcur[i], h) : 0u;
    hist[i] = 0;                       // reuse as per-wg cursor
  }
  __syncthreads();
  #pragma unroll
  for (int j = 0; j < EPTS; ++j)
    if (bn[j] >= 0) {
      unsigned p = rbase[bn[j]] + atomicAdd(&hist[bn[j]], 1u);
      binbuf[p] = pk[j];
    }
}

// ---------- pass 3: within-bin counting sort by local dst -> per-node CSR ----------
__global__ __launch_bounds__(512) void k_sort(const unsigned* binbuf, const unsigned* offs,
                                              const unsigned* gcnt, unsigned* csr,
                                              unsigned* offs2, float* dinv, int n, int e) {
  __shared__ unsigned hist[BINW];
  __shared__ unsigned scn[BINW];
  __shared__ unsigned cur[BINW];
  const int b = blockIdx.x, t = threadIdx.x;
  hist[t] = 0;
  __syncthreads();
  const unsigned off = offs[b], cnt = gcnt[b];
  for (unsigned i = t; i < cnt; i += 512)
    atomicAdd(&hist[binbuf[off + i] >> 17], 1u);
  __syncthreads();
  scn[t] = hist[t];
  __syncthreads();
  for (int d = 1; d < BINW; d <<= 1) {
    unsigned a = (t >= d) ? scn[t - d] : 0u;
    __syncthreads();
    scn[t] += a;
    __syncthreads();
  }
  {
    unsigned excl = scn[t] - hist[t];
    cur[t] = excl;
    int g = b * BINW + t;
    if (g < n) {
      offs2[g] = off + excl;
      dinv[g] = rsqrtf((float)(hist[t] + 1u));   // +1 self-loop
    }
  }
  if (b == 0 && t == 0) offs2[n] = (unsigned)e;  // sentinel
  __syncthreads();
  for (unsigned i = t; i < cnt; i += 512) {
    unsigned pk = binbuf[off + i];
    unsigned dl = pk >> 17;
    unsigned p = atomicAdd(&cur[dl], 1u);
    csr[off + p] = pk & 0x1FFFFu;
  }
}

// ---------- hs1 = dinv[n] * (x @ W1), channel-split into two [n][8] tables ----------
__global__ __launch_bounds__(256) void k_xw1(const void* x, const void* W1,
                                             const int* flags, const float* dinv,
                                             float* hs1a, float* hs1b, int n) {
  __shared__ float w[IN_F * HID];
  __shared__ float xt[16 * XT_LD];
  const int t = threadIdx.x;
  const int bf = flags[0];
  for (int i = t; i < IN_F * HID; i += 256) w[i] = loadF(W1, i, bf);
  const int n0 = blockIdx.x * 16;
  for (int i = t; i < 16 * IN_F; i += 256) {
    int rl = i >> 7, k = i & 127;
    int row = n0 + rl;
    xt[rl * XT_LD + k] = (row < n) ? loadF(x, (size_t)row * IN_F + k, bf) : 0.f;
  }
  __syncthreads();
  const int ln = t >> 4, c = t & 15;
  const int node = n0 + ln;
  if (node >= n) return;
  float acc = 0.f;
  #pragma unroll 16
  for (int k = 0; k < IN_F; ++k)
    acc = fmaf(xt[ln * XT_LD + k], w[k * HID + c], acc);
  const float v = dinv[node] * acc;
  if (c < 8) hs1a[(size_t)node * 8 + c] = v;
  else       hs1b[(size_t)node * 8 + (c - 8)] = v;
}

// ---------- layer-1 half-aggregation: 3.2MB table is XCD-L2-resident ----------
// 2 lanes/edge: sub = lane>>1 (32 edge slots), q = lane&1 (which float4 of the 32B row)
__global__ __launch_bounds__(256) void k_agg1h(const unsigned* csr, const unsigned* offs2,
                                               const float* dinv, const float* tbl,
                                               const void* b1, const int* flags,
                                               float* otbl, int n, int bofs) {
  const int wid = (blockIdx.x * 256 + threadIdx.x) >> 6;
  if (wid >= n) return;
  const int lane = threadIdx.x & 63;
  const int sub = lane >> 1, q = lane & 1;
  const unsigned off = offs2[wid];
  const unsigned cnt = offs2[wid + 1] - off;
  float4 acc = make_float4(0.f, 0.f, 0.f, 0.f);
  for (unsigned i = sub; i < cnt; i += 32) {
    unsigned s = __builtin_nontemporal_load(csr + off + i);
    const float4 v = ((const float4*)(tbl + (size_t)s * 8))[q];
    acc.x += v.x; acc.y += v.y; acc.z += v.z; acc.w += v.w;
  }
  #pragma unroll
  for (int m = 2; m < 64; m <<= 1) {
    acc.x += __shfl_xor(acc.x, m, 64);
    acc.y += __shfl_xor(acc.y, m, 64);
    acc.z += __shfl_xor(acc.z, m, 64);
    acc.w += __shfl_xor(acc.w, m, 64);
  }
  if (lane < 2) {
    const float di = dinv[wid];
    const float4 sv = ((const float4*)(tbl + (size_t)wid * 8))[q];
    const int bf = flags[0];
    float4 o;
    o.x = di * fmaxf(fmaf(di, acc.x + sv.x, loadF(b1, bofs + q * 4 + 0, bf)), 0.f);
    o.y = di * fmaxf(fmaf(di, acc.y + sv.y, loadF(b1, bofs + q * 4 + 1, bf)), 0.f);
    o.z = di * fmaxf(fmaf(di, acc.z + sv.z, loadF(b1, bofs + q * 4 + 2, bf)), 0.f);
    o.w = di * fmaxf(fmaf(di, acc.w + sv.w, loadF(b1, bofs + q * 4 + 3, bf)), 0.f);
    ((float4*)(otbl + (size_t)wid * 8))[q] = o;
  }
}

// ---------- layer-2 half-aggregation: z = dinv*(acc + self), no bias/relu ----------
__global__ __launch_bounds__(256) void k_agg2h(const unsigned* csr, const unsigned* offs2,
                                               const float* dinv, const float* tbl,
                                               float* otbl, int n) {
  const int wid = (blockIdx.x * 256 + threadIdx.x) >> 6;
  if (wid >= n) return;
  const int lane = threadIdx.x & 63;
  const int sub = lane >> 1, q = lane & 1;
  const unsigned off = offs2[wid];
  const unsigned cnt = offs2[wid + 1] - off;
  float4 acc = make_float4(0.f, 0.f, 0.f, 0.f);
  for (unsigned i = sub; i < cnt; i += 32) {
    unsigned s = __builtin_nontemporal_load(csr + off + i);
    const float4 v = ((const float4*)(tbl + (size_t)s * 8))[q];
    acc.x += v.x; acc.y += v.y; acc.z += v.z; acc.w += v.w;
  }
  #pragma unroll
  for (int m = 2; m < 64; m <<= 1) {
    acc.x += __shfl_xor(acc.x, m, 64);
    acc.y += __shfl_xor(acc.y, m, 64);
    acc.z += __shfl_xor(acc.z, m, 64);
    acc.w += __shfl_xor(acc.w, m, 64);
  }
  if (lane < 2) {
    const float di = dinv[wid];
    const float4 sv = ((const float4*)(tbl + (size_t)wid * 8))[q];
    float4 o;
    o.x = di * (acc.x + sv.x);
    o.y = di * (acc.y + sv.y);
    o.z = di * (acc.z + sv.z);
    o.w = di * (acc.w + sv.w);
    ((float4*)(otbl + (size_t)wid * 8))[q] = o;
  }
}

// ---------- epilogue: out = relu(z @ W2 + b2), streaming ----------
__global__ __launch_bounds__(256) void k_out(const float* za, const float* zb,
                                             const void* W2, const void* b2,
                                             const int* flags, void* out, int n) {
  __shared__ float w2s[HID * OUT_F];
  const int t = threadIdx.x;
  const int bf = flags[0];
  for (int i = t; i < HID * OUT_F; i += 256) w2s[i] = loadF(W2, i, bf);
  __syncthreads();
  const int wid = (blockIdx.x * 256 + t) >> 6;
  if (wid >= n) return;
  const int lane = t & 63;
  float zv = 0.f;
  if (lane < 8)       zv = za[(size_t)wid * 8 + lane];
  else if (lane < 16) zv = zb[(size_t)wid * 8 + (lane - 8)];
  float o = loadF(b2, lane, bf);
  #pragma unroll
  for (int k = 0; k < HID; ++k)
    o = fmaf(__shfl(zv, k, 64), w2s[k * OUT_F + lane], o);
  o = fmaxf(o, 0.f);
  size_t oi = (size_t)wid * OUT_F + lane;
  if (bf) ((__hip_bfloat16*)out)[oi] = __float2bfloat16(o);
  else    ((float*)out)[oi] = o;
}

extern "C" void kernel_launch(void* const* d_in, const int* in_sizes, int n_in,
                              void* d_out, int out_size, void* d_ws, size_t ws_size,
                              hipStream_t stream) {
  const void* x  = d_in[0];
  const void* ei = d_in[1];
  const void* W1 = d_in[2];
  const void* b1 = d_in[3];
  const void* W2 = d_in[4];
  const void* b2 = d_in[5];
  const int n = in_sizes[0] / IN_F;
  const int e = in_sizes[1] / 2;
  const int nb = (n + BINW - 1) / BINW;

  char* p = (char*)d_ws;
  auto alloc = [&](size_t bytes) -> char* {
    char* r = p;
    p += (bytes + 255) & ~(size_t)255;
    return r;
  };
  int*      flags  = (int*)alloc(256);
  unsigned* gcnt   = (unsigned*)alloc(MAXNB * 4);
  unsigned* offs   = (unsigned*)alloc(MAXNB * 4);
  unsigned* gcur   = (unsigned*)alloc(MAXNB * 4);
  float*    dinv   = (float*)alloc((size_t)n * 4);
  unsigned* offs2  = (unsigned*)alloc(((size_t)n + 1) * 4);
  float*    hs1a   = (float*)alloc((size_t)n * 32);   // [n][8] f32
  float*    hs1b   = (float*)alloc((size_t)n * 32);
  float*    hda    = (float*)alloc((size_t)n * 32);
  float*    hdb    = (float*)alloc((size_t)n * 32);
  unsigned* binbuf = (unsigned*)alloc((size_t)e * 4);
  unsigned* csr    = (unsigned*)alloc((size_t)e * 4);
  // z vectors reuse the hs1 buffers (hs1 dead once hd is built)
  float* za = hs1a;
  float* zb = hs1b;

  const int nbE  = (e + 256 * EPT  - 1) / (256 * EPT);
  const int nbES = (e + 256 * EPTS - 1) / (256 * EPTS);
  const int nbW  = (n + 3) / 4;   // wave-per-node kernels, 4 waves/block

  k_detect<<<1, 256, 0, stream>>>(x, ei, flags);
  hipMemsetAsync(gcnt, 0, MAXNB * 4, stream);
  k_bincount<<<nbE, 256, 0, stream>>>(ei, flags, gcnt, e, nb);
  k_scan<<<1, 256, 0, stream>>>(gcnt, offs, gcur, nb);
  k_scatter<<<nbES, 256, 0, stream>>>(ei, flags, gcur, binbuf, e, nb);
  k_sort<<<nb, 512, 0, stream>>>(binbuf, offs, gcnt, csr, offs2, dinv, n, e);
  k_xw1<<<(n + 15) / 16, 256, 0, stream>>>(x, W1, flags, dinv, hs1a, hs1b, n);
  k_agg1h<<<nbW, 256, 0, stream>>>(csr, offs2, dinv, hs1a, b1, flags, hda, n, 0);
  k_agg1h<<<nbW, 256, 0, stream>>>(csr, offs2, dinv, hs1b, b1, flags, hdb, n, 8);
  k_agg2h<<<nbW, 256, 0, stream>>>(csr, offs2, dinv, hda, za, n);
  k_agg2h<<<nbW, 256, 0, stream>>>(csr, offs2, dinv, hdb, zb, n);
  k_out<<<(n * 64 + 255) / 256, 256, 0, stream>>>(za, zb, W2, b2, flags, d_out, n);
}

// Round 7
// 271.891 us; speedup vs baseline: 1.3128x; 1.2780x over previous
//
#include <hip/hip_runtime.h>
#include <hip/hip_bf16.h>

#define IN_F 128
#define HID 16
#define OUT_F 64
#define XT_LD 132   // padded LDS stride for x tile in k_xw1
#define BINW 512    // nodes per bin (dst >> 9)
#define BSH 9
#define MAXNB 256   // supports n <= 131072
#define EPT 16      // edges per thread in bincount
#define EPTS 16     // edges per thread in scatter

// ---------- dtype-flex helpers (device-side runtime dtype detection) ----------
__device__ __forceinline__ float loadF(const void* p, size_t i, int bf) {
  if (bf) {
    unsigned v = ((unsigned)((const unsigned short*)p)[i]) << 16;
    float f; __builtin_memcpy(&f, &v, 4); return f;
  }
  return ((const float*)p)[i];
}
__device__ __forceinline__ int loadE_nt(const void* p, size_t i, int i64) {
  if (i64) return __builtin_nontemporal_load((const int*)p + 2 * i);  // little-endian low word
  return __builtin_nontemporal_load((const int*)p + i);
}
// bf16 pack/unpack (RNE, matches __float2bfloat16)
__device__ __forceinline__ unsigned short f2bf(float f) {
  unsigned u; __builtin_memcpy(&u, &f, 4);
  return (unsigned short)((u + 0x7FFFu + ((u >> 16) & 1u)) >> 16);
}
__device__ __forceinline__ float bf2f(unsigned short h) {
  unsigned u = ((unsigned)h) << 16;
  float f; __builtin_memcpy(&f, &u, 4); return f;
}
// unpack uint4 (8 bf16) -> 8 f32, accumulate
__device__ __forceinline__ void acc8(const uint4 v, float* a) {
  const unsigned u[4] = {v.x, v.y, v.z, v.w};
  #pragma unroll
  for (int j = 0; j < 4; ++j) {
    unsigned lo = u[j] << 16, hi = u[j] & 0xFFFF0000u;
    float fl, fh; __builtin_memcpy(&fl, &lo, 4); __builtin_memcpy(&fh, &hi, 4);
    a[2 * j] += fl; a[2 * j + 1] += fh;
  }
}
__device__ __forceinline__ void unp8(const uint4 v, float* a) {
  const unsigned u[4] = {v.x, v.y, v.z, v.w};
  #pragma unroll
  for (int j = 0; j < 4; ++j) {
    unsigned lo = u[j] << 16, hi = u[j] & 0xFFFF0000u;
    __builtin_memcpy(&a[2 * j], &lo, 4); __builtin_memcpy(&a[2 * j + 1], &hi, 4);
  }
}
__device__ __forceinline__ uint4 pk8(const float* r) {
  uint4 o;
  o.x = (unsigned)f2bf(r[0]) | ((unsigned)f2bf(r[1]) << 16);
  o.y = (unsigned)f2bf(r[2]) | ((unsigned)f2bf(r[3]) << 16);
  o.z = (unsigned)f2bf(r[4]) | ((unsigned)f2bf(r[5]) << 16);
  o.w = (unsigned)f2bf(r[6]) | ((unsigned)f2bf(r[7]) << 16);
  return o;
}

// flags[0] = 1 if float tensors are bf16; flags[1] = 1 if edge_index is int64
__global__ void k_detect(const void* x, const void* ei, int* flags) {
  __shared__ int c_ok, c_hi;
  int t = threadIdx.x;
  if (t == 0) { c_ok = 0; c_hi = 0; }
  __syncthreads();
  const float* xf = (const float*)x;
  int ok = 0;
  for (int i = t; i < 1024; i += 256) {
    float v = fabsf(xf[i]);
    if (v > 1e-4f && v < 1e4f) ok++;
  }
  const int* ep = (const int*)ei;
  int hi = 0;
  for (int i = t; i < 1024; i += 256)
    if (ep[2 * i + 1] != 0) hi++;
  atomicAdd(&c_ok, ok);
  atomicAdd(&c_hi, hi);
  __syncthreads();
  if (t == 0) {
    flags[0] = (c_ok < 512) ? 1 : 0;
    flags[1] = (c_hi == 0) ? 1 : 0;
  }
}

// ---------- pass 1: per-bin edge counts ----------
__global__ __launch_bounds__(256) void k_bincount(const void* ei, const int* flags,
                                                  unsigned* gcnt, int e, int nb) {
  __shared__ unsigned hist[MAXNB];
  const int t = threadIdx.x;
  for (int i = t; i < nb; i += 256) hist[i] = 0;
  __syncthreads();
  const int i64 = flags[1];
  const size_t base = (size_t)blockIdx.x * (256 * EPT);
  #pragma unroll
  for (int j = 0; j < EPT; ++j) {
    size_t idx = base + (size_t)j * 256 + t;
    if (idx < (size_t)e) {
      int d = loadE_nt(ei, (size_t)e + idx, i64);
      atomicAdd(&hist[d >> BSH], 1u);
    }
  }
  __syncthreads();
  for (int i = t; i < nb; i += 256)
    if (hist[i]) atomicAdd(&gcnt[i], hist[i]);
}

// ---------- exclusive scan over bin counts ----------
__global__ __launch_bounds__(256) void k_scan(const unsigned* gcnt, unsigned* offs,
                                              unsigned* gcur, int nb) {
  __shared__ unsigned s[256];
  const int t = threadIdx.x;
  unsigned c[4]; unsigned sum = 0;
  #pragma unroll
  for (int j = 0; j < 4; ++j) {
    int i = t * 4 + j;
    c[j] = (i < nb) ? gcnt[i] : 0u;
    sum += c[j];
  }
  s[t] = sum; __syncthreads();
  for (int d = 1; d < 256; d <<= 1) {
    unsigned a = (t >= d) ? s[t - d] : 0u;
    __syncthreads();
    s[t] += a;
    __syncthreads();
  }
  unsigned run = s[t] - sum;
  #pragma unroll
  for (int j = 0; j < 4; ++j) {
    int i = t * 4 + j;
    if (i < nb) { offs[i] = run; gcur[i] = run; run += c[j]; }
  }
}

// ---------- pass 2: scatter edges into bins (wg-bulk reservation, PLAIN stores) ----------
__global__ __launch_bounds__(256) void k_scatter(const void* ei, const int* flags,
                                                 unsigned* gcur, unsigned* binbuf,
                                                 int e, int nb) {
  __shared__ unsigned hist[MAXNB];
  __shared__ unsigned rbase[MAXNB];
  const int t = threadIdx.x;
  for (int i = t; i < nb; i += 256) hist[i] = 0;
  __syncthreads();
  const int i64 = flags[1];
  const size_t base = (size_t)blockIdx.x * (256 * EPTS);
  unsigned pk[EPTS]; int bn[EPTS];
  #pragma unroll
  for (int j = 0; j < EPTS; ++j) {
    size_t idx = base + (size_t)j * 256 + t;
    if (idx < (size_t)e) {
      int s = loadE_nt(ei, idx, i64);
      int d = loadE_nt(ei, (size_t)e + idx, i64);
      bn[j] = d >> BSH;
      pk[j] = (unsigned)s | ((unsigned)(d & (BINW - 1)) << 17);
      atomicAdd(&hist[bn[j]], 1u);
    } else bn[j] = -1;
  }
  __syncthreads();
  for (int i = t; i < nb; i += 256) {
    unsigned h = hist[i];
    rbase[i] = h ? atomicAdd(&gcur[i], h) : 0u;
    hist[i] = 0;
  }
  __syncthreads();
  #pragma unroll
  for (int j = 0; j < EPTS; ++j)
    if (bn[j] >= 0) {
      unsigned p = rbase[bn[j]] + atomicAdd(&hist[bn[j]], 1u);
      binbuf[p] = pk[j];
    }
}

// ---------- pass 3: within-bin counting sort -> per-node CSR + dinv ----------
__global__ __launch_bounds__(512) void k_sort(const unsigned* binbuf, const unsigned* offs,
                                              const unsigned* gcnt, unsigned* csr,
                                              unsigned* offs2, float* dinv, int n, int e) {
  __shared__ unsigned hist[BINW];
  __shared__ unsigned scn[BINW];
  __shared__ unsigned cur[BINW];
  const int b = blockIdx.x, t = threadIdx.x;
  hist[t] = 0;
  __syncthreads();
  const unsigned off = offs[b], cnt = gcnt[b];
  for (unsigned i = t; i < cnt; i += 512)
    atomicAdd(&hist[binbuf[off + i] >> 17], 1u);
  __syncthreads();
  scn[t] = hist[t];
  __syncthreads();
  for (int d = 1; d < BINW; d <<= 1) {
    unsigned a = (t >= d) ? scn[t - d] : 0u;
    __syncthreads();
    scn[t] += a;
    __syncthreads();
  }
  {
    unsigned excl = scn[t] - hist[t];
    cur[t] = excl;
    int g = b * BINW + t;
    if (g < n) {
      offs2[g] = off + excl;
      dinv[g] = rsqrtf((float)(hist[t] + 1u));   // +1 self-loop
    }
  }
  if (b == 0 && t == 0) offs2[n] = (unsigned)e;
  __syncthreads();
  for (unsigned i = t; i < cnt; i += 512) {
    unsigned pk = binbuf[off + i];
    unsigned dl = pk >> 17;
    unsigned p = atomicAdd(&cur[dl], 1u);
    csr[off + p] = pk & 0x1FFFFu;
  }
}

// ---------- hs1 = bf16( dinv[n] * (x @ W1) ), [n][16] bf16 (3.2MB, L2-resident) ----------
__global__ __launch_bounds__(256) void k_xw1(const void* x, const void* W1,
                                             const int* flags, const float* dinv,
                                             unsigned short* hs1, int n) {
  __shared__ float w[IN_F * HID];
  __shared__ float xt[16 * XT_LD];
  const int t = threadIdx.x;
  const int bf = flags[0];
  for (int i = t; i < IN_F * HID; i += 256) w[i] = loadF(W1, i, bf);
  const int n0 = blockIdx.x * 16;
  for (int i = t; i < 16 * IN_F; i += 256) {
    int rl = i >> 7, k = i & 127;
    int row = n0 + rl;
    xt[rl * XT_LD + k] = (row < n) ? loadF(x, (size_t)row * IN_F + k, bf) : 0.f;
  }
  __syncthreads();
  const int ln = t >> 4, c = t & 15;
  const int node = n0 + ln;
  if (node >= n) return;
  float acc = 0.f;
  #pragma unroll 16
  for (int k = 0; k < IN_F; ++k)
    acc = fmaf(xt[ln * XT_LD + k], w[k * HID + c], acc);
  hs1[(size_t)node * HID + c] = f2bf(dinv[node] * acc);
}

// ---------- layer-1 aggregation: wave-per-node, bf16 gather, f32 accumulate ----------
// 2 lanes/edge: sub = lane>>1 (32 edge slots), q = lane&1 (which 16B half of 32B row)
__global__ __launch_bounds__(256) void k_agg1(const unsigned* csr, const unsigned* offs2,
                                              const float* dinv, const uint4* tbl,
                                              const void* b1, const int* flags,
                                              uint4* hd, int n) {
  const int wid = (blockIdx.x * 256 + threadIdx.x) >> 6;
  if (wid >= n) return;
  const int lane = threadIdx.x & 63;
  const int sub = lane >> 1, q = lane & 1;
  const unsigned off = offs2[wid];
  const unsigned cnt = offs2[wid + 1] - off;
  float a[8] = {0, 0, 0, 0, 0, 0, 0, 0};
  for (unsigned i = sub; i < cnt; i += 32) {
    unsigned s = __builtin_nontemporal_load(csr + off + i);
    acc8(tbl[(size_t)s * 2 + q], a);
  }
  #pragma unroll
  for (int m = 2; m < 64; m <<= 1) {
    #pragma unroll
    for (int j = 0; j < 8; ++j) a[j] += __shfl_xor(a[j], m, 64);
  }
  if (lane < 2) {
    const float di = dinv[wid];
    float sv[8]; unp8(tbl[(size_t)wid * 2 + q], sv);
    const int bf = flags[0];
    float r[8];
    #pragma unroll
    for (int j = 0; j < 8; ++j)
      r[j] = di * fmaxf(fmaf(di, a[j] + sv[j], loadF(b1, q * 8 + j, bf)), 0.f);
    hd[(size_t)wid * 2 + q] = pk8(r);
  }
}

// ---------- layer-2 aggregation + fused 16->64 transform + relu ----------
__global__ __launch_bounds__(256) void k_agg2(const unsigned* csr, const unsigned* offs2,
                                              const float* dinv, const uint4* tbl,
                                              const void* W2, const void* b2,
                                              const int* flags, void* out, int n) {
  __shared__ float w2s[HID * OUT_F];
  const int t = threadIdx.x;
  const int bf = flags[0];
  for (int i = t; i < HID * OUT_F; i += 256) w2s[i] = loadF(W2, i, bf);
  __syncthreads();
  const int wid = (blockIdx.x * 256 + t) >> 6;
  if (wid >= n) return;
  const int lane = t & 63;
  const int sub = lane >> 1, q = lane & 1;
  const unsigned off = offs2[wid];
  const unsigned cnt = offs2[wid + 1] - off;
  float a[8] = {0, 0, 0, 0, 0, 0, 0, 0};
  for (unsigned i = sub; i < cnt; i += 32) {
    unsigned s = __builtin_nontemporal_load(csr + off + i);
    acc8(tbl[(size_t)s * 2 + q], a);
  }
  #pragma unroll
  for (int m = 2; m < 64; m <<= 1) {
    #pragma unroll
    for (int j = 0; j < 8; ++j) a[j] += __shfl_xor(a[j], m, 64);
  }
  // lanes 0,1 hold channel sums; compute z = dinv*(acc+self) there
  const float di = dinv[wid];
  float sv[8]; unp8(tbl[(size_t)wid * 2 + q], sv);
  float r[8];
  #pragma unroll
  for (int j = 0; j < 8; ++j) r[j] = di * (a[j] + sv[j]);
  // broadcast all 16 z values to all lanes
  float zk[16];
  #pragma unroll
  for (int j = 0; j < 8; ++j) {
    zk[j]     = __shfl(r[j], 0, 64);
    zk[8 + j] = __shfl(r[j], 1, 64);
  }
  float o = loadF(b2, lane, bf);
  #pragma unroll
  for (int k = 0; k < HID; ++k) o = fmaf(zk[k], w2s[k * OUT_F + lane], o);
  o = fmaxf(o, 0.f);
  size_t oi = (size_t)wid * OUT_F + lane;
  if (bf) ((__hip_bfloat16*)out)[oi] = __float2bfloat16(o);
  else    ((float*)out)[oi] = o;
}

extern "C" void kernel_launch(void* const* d_in, const int* in_sizes, int n_in,
                              void* d_out, int out_size, void* d_ws, size_t ws_size,
                              hipStream_t stream) {
  const void* x  = d_in[0];
  const void* ei = d_in[1];
  const void* W1 = d_in[2];
  const void* b1 = d_in[3];
  const void* W2 = d_in[4];
  const void* b2 = d_in[5];
  const int n = in_sizes[0] / IN_F;
  const int e = in_sizes[1] / 2;
  const int nb = (n + BINW - 1) / BINW;

  char* p = (char*)d_ws;
  auto alloc = [&](size_t bytes) -> char* {
    char* r = p;
    p += (bytes + 255) & ~(size_t)255;
    return r;
  };
  int*            flags  = (int*)alloc(256);
  unsigned*       gcnt   = (unsigned*)alloc(MAXNB * 4);
  unsigned*       offs   = (unsigned*)alloc(MAXNB * 4);
  unsigned*       gcur   = (unsigned*)alloc(MAXNB * 4);
  float*          dinv   = (float*)alloc((size_t)n * 4);
  unsigned*       offs2  = (unsigned*)alloc(((size_t)n + 1) * 4);
  unsigned short* hs1    = (unsigned short*)alloc((size_t)n * HID * 2);  // bf16 [n][16]
  unsigned short* hd     = (unsigned short*)alloc((size_t)n * HID * 2);  // bf16 [n][16]
  unsigned*       binbuf = (unsigned*)alloc((size_t)e * 4);
  unsigned*       csr    = (unsigned*)alloc((size_t)e * 4);

  const int nbE  = (e + 256 * EPT  - 1) / (256 * EPT);
  const int nbES = (e + 256 * EPTS - 1) / (256 * EPTS);
  const int nbW  = (n + 3) / 4;   // wave-per-node kernels, 4 waves/block

  k_detect<<<1, 256, 0, stream>>>(x, ei, flags);
  hipMemsetAsync(gcnt, 0, MAXNB * 4, stream);
  k_bincount<<<nbE, 256, 0, stream>>>(ei, flags, gcnt, e, nb);
  k_scan<<<1, 256, 0, stream>>>(gcnt, offs, gcur, nb);
  k_scatter<<<nbES, 256, 0, stream>>>(ei, flags, gcur, binbuf, e, nb);
  k_sort<<<nb, 512, 0, stream>>>(binbuf, offs, gcnt, csr, offs2, dinv, n, e);
  k_xw1<<<(n + 15) / 16, 256, 0, stream>>>(x, W1, flags, dinv, hs1, n);
  k_agg1<<<nbW, 256, 0, stream>>>(csr, offs2, dinv, (const uint4*)hs1, b1, flags,
                                  (uint4*)hd, n);
  k_agg2<<<nbW, 256, 0, stream>>>(csr, offs2, dinv, (const uint4*)hd, W2, b2, flags,
                                  d_out, n);
}

// Round 8
// 224.940 us; speedup vs baseline: 1.5868x; 1.2087x over previous
//
#include <hip/hip_runtime.h>
#include <hip/hip_bf16.h>

#define IN_F 128
#define HID 16
#define OUT_F 64
#define XT_LD 132   // padded LDS stride for x tile in k_xw1
#define BINW 512    // nodes per bin (dst >> 9)
#define BSH 9
#define MAXNB 256   // supports n <= 131072
#define EPT 16      // edges per thread in bincount
#define EPTS 16     // edges per thread in scatter

// ---------- dtype-flex helpers (device-side runtime dtype detection) ----------
__device__ __forceinline__ float loadF(const void* p, size_t i, int bf) {
  if (bf) {
    unsigned v = ((unsigned)((const unsigned short*)p)[i]) << 16;
    float f; __builtin_memcpy(&f, &v, 4); return f;
  }
  return ((const float*)p)[i];
}
__device__ __forceinline__ int loadE_nt(const void* p, size_t i, int i64) {
  if (i64) return __builtin_nontemporal_load((const int*)p + 2 * i);  // little-endian low word
  return __builtin_nontemporal_load((const int*)p + i);
}
// bf16 pack/unpack (RNE, matches __float2bfloat16)
__device__ __forceinline__ unsigned short f2bf(float f) {
  unsigned u; __builtin_memcpy(&u, &f, 4);
  return (unsigned short)((u + 0x7FFFu + ((u >> 16) & 1u)) >> 16);
}
// unpack uint4 (8 bf16) -> 8 f32, accumulate
__device__ __forceinline__ void acc8(const uint4 v, float* a) {
  const unsigned u[4] = {v.x, v.y, v.z, v.w};
  #pragma unroll
  for (int j = 0; j < 4; ++j) {
    unsigned lo = u[j] << 16, hi = u[j] & 0xFFFF0000u;
    float fl, fh; __builtin_memcpy(&fl, &lo, 4); __builtin_memcpy(&fh, &hi, 4);
    a[2 * j] += fl; a[2 * j + 1] += fh;
  }
}
__device__ __forceinline__ void unp8(const uint4 v, float* a) {
  const unsigned u[4] = {v.x, v.y, v.z, v.w};
  #pragma unroll
  for (int j = 0; j < 4; ++j) {
    unsigned lo = u[j] << 16, hi = u[j] & 0xFFFF0000u;
    __builtin_memcpy(&a[2 * j], &lo, 4); __builtin_memcpy(&a[2 * j + 1], &hi, 4);
  }
}
__device__ __forceinline__ uint4 pk8(const float* r) {
  uint4 o;
  o.x = (unsigned)f2bf(r[0]) | ((unsigned)f2bf(r[1]) << 16);
  o.y = (unsigned)f2bf(r[2]) | ((unsigned)f2bf(r[3]) << 16);
  o.z = (unsigned)f2bf(r[4]) | ((unsigned)f2bf(r[5]) << 16);
  o.w = (unsigned)f2bf(r[6]) | ((unsigned)f2bf(r[7]) << 16);
  return o;
}

// flags[0] = 1 if float tensors are bf16; flags[1] = 1 if edge_index is int64
__global__ void k_detect(const void* x, const void* ei, int* flags) {
  __shared__ int c_ok, c_hi;
  int t = threadIdx.x;
  if (t == 0) { c_ok = 0; c_hi = 0; }
  __syncthreads();
  const float* xf = (const float*)x;
  int ok = 0;
  for (int i = t; i < 1024; i += 256) {
    float v = fabsf(xf[i]);
    if (v > 1e-4f && v < 1e4f) ok++;
  }
  const int* ep = (const int*)ei;
  int hi = 0;
  for (int i = t; i < 1024; i += 256)
    if (ep[2 * i + 1] != 0) hi++;
  atomicAdd(&c_ok, ok);
  atomicAdd(&c_hi, hi);
  __syncthreads();
  if (t == 0) {
    flags[0] = (c_ok < 512) ? 1 : 0;
    flags[1] = (c_hi == 0) ? 1 : 0;
  }
}

// ---------- pass 1: per-bin edge counts ----------
__global__ __launch_bounds__(256) void k_bincount(const void* ei, const int* flags,
                                                  unsigned* gcnt, int e, int nb) {
  __shared__ unsigned hist[MAXNB];
  const int t = threadIdx.x;
  for (int i = t; i < nb; i += 256) hist[i] = 0;
  __syncthreads();
  const int i64 = flags[1];
  const size_t base = (size_t)blockIdx.x * (256 * EPT);
  #pragma unroll
  for (int j = 0; j < EPT; ++j) {
    size_t idx = base + (size_t)j * 256 + t;
    if (idx < (size_t)e) {
      int d = loadE_nt(ei, (size_t)e + idx, i64);
      atomicAdd(&hist[d >> BSH], 1u);
    }
  }
  __syncthreads();
  for (int i = t; i < nb; i += 256)
    if (hist[i]) atomicAdd(&gcnt[i], hist[i]);
}

// ---------- exclusive scan over bin counts ----------
__global__ __launch_bounds__(256) void k_scan(const unsigned* gcnt, unsigned* offs,
                                              unsigned* gcur, int nb) {
  __shared__ unsigned s[256];
  const int t = threadIdx.x;
  unsigned c[4]; unsigned sum = 0;
  #pragma unroll
  for (int j = 0; j < 4; ++j) {
    int i = t * 4 + j;
    c[j] = (i < nb) ? gcnt[i] : 0u;
    sum += c[j];
  }
  s[t] = sum; __syncthreads();
  for (int d = 1; d < 256; d <<= 1) {
    unsigned a = (t >= d) ? s[t - d] : 0u;
    __syncthreads();
    s[t] += a;
    __syncthreads();
  }
  unsigned run = s[t] - sum;
  #pragma unroll
  for (int j = 0; j < 4; ++j) {
    int i = t * 4 + j;
    if (i < nb) { offs[i] = run; gcur[i] = run; run += c[j]; }
  }
}

// ---------- pass 2: scatter edges into bins (wg-bulk reservation, PLAIN stores) ----------
__global__ __launch_bounds__(256) void k_scatter(const void* ei, const int* flags,
                                                 unsigned* gcur, unsigned* binbuf,
                                                 int e, int nb) {
  __shared__ unsigned hist[MAXNB];
  __shared__ unsigned rbase[MAXNB];
  const int t = threadIdx.x;
  for (int i = t; i < nb; i += 256) hist[i] = 0;
  __syncthreads();
  const int i64 = flags[1];
  const size_t base = (size_t)blockIdx.x * (256 * EPTS);
  unsigned pk[EPTS]; int bn[EPTS];
  #pragma unroll
  for (int j = 0; j < EPTS; ++j) {
    size_t idx = base + (size_t)j * 256 + t;
    if (idx < (size_t)e) {
      int s = loadE_nt(ei, idx, i64);
      int d = loadE_nt(ei, (size_t)e + idx, i64);
      bn[j] = d >> BSH;
      pk[j] = (unsigned)s | ((unsigned)(d & (BINW - 1)) << 17);
      atomicAdd(&hist[bn[j]], 1u);
    } else bn[j] = -1;
  }
  __syncthreads();
  for (int i = t; i < nb; i += 256) {
    unsigned h = hist[i];
    rbase[i] = h ? atomicAdd(&gcur[i], h) : 0u;
    hist[i] = 0;
  }
  __syncthreads();
  #pragma unroll
  for (int j = 0; j < EPTS; ++j)
    if (bn[j] >= 0) {
      unsigned p = rbase[bn[j]] + atomicAdd(&hist[bn[j]], 1u);
      binbuf[p] = pk[j];
    }
}

// ---------- pass 3: within-bin counting sort -> per-node CSR + dinv ----------
__global__ __launch_bounds__(512) void k_sort(const unsigned* binbuf, const unsigned* offs,
                                              const unsigned* gcnt, unsigned* csr,
                                              unsigned* offs2, float* dinv, int n, int e) {
  __shared__ unsigned hist[BINW];
  __shared__ unsigned scn[BINW];
  __shared__ unsigned cur[BINW];
  const int b = blockIdx.x, t = threadIdx.x;
  hist[t] = 0;
  __syncthreads();
  const unsigned off = offs[b], cnt = gcnt[b];
  for (unsigned i = t; i < cnt; i += 512)
    atomicAdd(&hist[binbuf[off + i] >> 17], 1u);
  __syncthreads();
  scn[t] = hist[t];
  __syncthreads();
  for (int d = 1; d < BINW; d <<= 1) {
    unsigned a = (t >= d) ? scn[t - d] : 0u;
    __syncthreads();
    scn[t] += a;
    __syncthreads();
  }
  {
    unsigned excl = scn[t] - hist[t];
    cur[t] = excl;
    int g = b * BINW + t;
    if (g < n) {
      offs2[g] = off + excl;
      dinv[g] = rsqrtf((float)(hist[t] + 1u));   // +1 self-loop
    }
  }
  if (b == 0 && t == 0) offs2[n] = (unsigned)e;
  __syncthreads();
  for (unsigned i = t; i < cnt; i += 512) {
    unsigned pk = binbuf[off + i];
    unsigned dl = pk >> 17;
    unsigned p = atomicAdd(&cur[dl], 1u);
    csr[off + p] = pk & 0x1FFFFu;
  }
}

// ---------- hs1 = bf16( dinv[n] * (x @ W1) ), [n][16] bf16 (3.2MB, L2-resident) ----------
__global__ __launch_bounds__(256) void k_xw1(const void* x, const void* W1,
                                             const int* flags, const float* dinv,
                                             unsigned short* hs1, int n) {
  __shared__ float w[IN_F * HID];
  __shared__ float xt[16 * XT_LD];
  const int t = threadIdx.x;
  const int bf = flags[0];
  for (int i = t; i < IN_F * HID; i += 256) w[i] = loadF(W1, i, bf);
  const int n0 = blockIdx.x * 16;
  if (!bf) {
    // vectorized f32 path: float4 loads (16B/lane)
    const float4* xv = (const float4*)x;
    for (int i = t; i < 16 * (IN_F / 4); i += 256) {
      int rl = i >> 5, k4 = i & 31;
      int row = n0 + rl;
      float4 v = (row < n) ? xv[(size_t)row * 32 + k4]
                           : make_float4(0.f, 0.f, 0.f, 0.f);
      float* xp = xt + rl * XT_LD + k4 * 4;
      xp[0] = v.x; xp[1] = v.y; xp[2] = v.z; xp[3] = v.w;
    }
  } else {
    for (int i = t; i < 16 * IN_F; i += 256) {
      int rl = i >> 7, k = i & 127;
      int row = n0 + rl;
      xt[rl * XT_LD + k] = (row < n) ? loadF(x, (size_t)row * IN_F + k, bf) : 0.f;
    }
  }
  __syncthreads();
  const int ln = t >> 4, c = t & 15;
  const int node = n0 + ln;
  if (node >= n) return;
  float acc = 0.f;
  #pragma unroll 16
  for (int k = 0; k < IN_F; ++k)
    acc = fmaf(xt[ln * XT_LD + k], w[k * HID + c], acc);
  hs1[(size_t)node * HID + c] = f2bf(dinv[node] * acc);
}

// ---------- layer-1 aggregation: 4 nodes/wave (16 lanes/node), bf16 gather ----------
// lane16 = lane&15; sub = lane16>>1 (8 edge slots), q = lane16&1 (16B half of row)
__global__ __launch_bounds__(256) void k_agg1(const unsigned* csr, const unsigned* offs2,
                                              const float* dinv, const uint4* tbl,
                                              const void* b1, const int* flags,
                                              uint4* hd, int n) {
  const int wave = (blockIdx.x * 256 + threadIdx.x) >> 6;
  const int lane = threadIdx.x & 63;
  const int g = lane >> 4, lane16 = lane & 15;
  const int node = wave * 4 + g;
  if (node >= n) return;
  const int sub = lane16 >> 1, q = lane16 & 1;
  const unsigned off = offs2[node];
  const unsigned cnt = offs2[node + 1] - off;
  float a[8] = {0, 0, 0, 0, 0, 0, 0, 0};
  for (unsigned i = sub; i < cnt; i += 8) {
    unsigned s = __builtin_nontemporal_load(csr + off + i);
    acc8(tbl[(size_t)s * 2 + q], a);
  }
  // reduce over 8 slots within the 16-lane group (parity-preserving)
  #pragma unroll
  for (int m = 2; m < 16; m <<= 1) {
    #pragma unroll
    for (int j = 0; j < 8; ++j) a[j] += __shfl_xor(a[j], m, 64);
  }
  if (lane16 < 2) {
    const float di = dinv[node];
    float sv[8]; unp8(tbl[(size_t)node * 2 + q], sv);
    const int bf = flags[0];
    float r[8];
    #pragma unroll
    for (int j = 0; j < 8; ++j)
      r[j] = di * fmaxf(fmaf(di, a[j] + sv[j], loadF(b1, q * 8 + j, bf)), 0.f);
    hd[(size_t)node * 2 + q] = pk8(r);
  }
}

// ---------- layer-2 aggregation + fused 16->64 transform + relu, 4 nodes/wave ----------
__global__ __launch_bounds__(256) void k_agg2(const unsigned* csr, const unsigned* offs2,
                                              const float* dinv, const uint4* tbl,
                                              const void* W2, const void* b2,
                                              const int* flags, void* out, int n) {
  __shared__ float w2s[HID * OUT_F];
  const int t = threadIdx.x;
  const int bf = flags[0];
  for (int i = t; i < HID * OUT_F; i += 256) w2s[i] = loadF(W2, i, bf);
  __syncthreads();
  const int wave = (blockIdx.x * 256 + t) >> 6;
  const int lane = t & 63;
  const int g = lane >> 4, lane16 = lane & 15;
  const int node = wave * 4 + g;
  if (node >= n) return;
  const int sub = lane16 >> 1, q = lane16 & 1;
  const unsigned off = offs2[node];
  const unsigned cnt = offs2[node + 1] - off;
  float a[8] = {0, 0, 0, 0, 0, 0, 0, 0};
  for (unsigned i = sub; i < cnt; i += 8) {
    unsigned s = __builtin_nontemporal_load(csr + off + i);
    acc8(tbl[(size_t)s * 2 + q], a);
  }
  #pragma unroll
  for (int m = 2; m < 16; m <<= 1) {
    #pragma unroll
    for (int j = 0; j < 8; ++j) a[j] += __shfl_xor(a[j], m, 64);
  }
  // every lane now holds its parity's total; z = dinv*(acc+self)
  const float di = dinv[node];
  float sv[8]; unp8(tbl[(size_t)node * 2 + q], sv);
  float zk[16];
  #pragma unroll
  for (int j = 0; j < 8; ++j) {
    float r = di * (a[j] + sv[j]);
    zk[q * 8 + j] = r;
    zk[(1 - q) * 8 + j] = __shfl_xor(r, 1, 64);   // grab the other parity's channels
  }
  // each lane computes 4 of the 64 outputs: o = lane16*4 + jj
  const int ob = lane16 * 4;
  float o0 = loadF(b2, ob + 0, bf), o1 = loadF(b2, ob + 1, bf);
  float o2 = loadF(b2, ob + 2, bf), o3 = loadF(b2, ob + 3, bf);
  #pragma unroll
  for (int k = 0; k < HID; ++k) {
    const float* wr = w2s + k * OUT_F + ob;
    o0 = fmaf(zk[k], wr[0], o0);
    o1 = fmaf(zk[k], wr[1], o1);
    o2 = fmaf(zk[k], wr[2], o2);
    o3 = fmaf(zk[k], wr[3], o3);
  }
  o0 = fmaxf(o0, 0.f); o1 = fmaxf(o1, 0.f);
  o2 = fmaxf(o2, 0.f); o3 = fmaxf(o3, 0.f);
  const size_t oi = (size_t)node * OUT_F + ob;
  if (bf) {
    __hip_bfloat16* op = (__hip_bfloat16*)out + oi;
    op[0] = __float2bfloat16(o0); op[1] = __float2bfloat16(o1);
    op[2] = __float2bfloat16(o2); op[3] = __float2bfloat16(o3);
  } else {
    float4 v = make_float4(o0, o1, o2, o3);
    *(float4*)((float*)out + oi) = v;
  }
}

extern "C" void kernel_launch(void* const* d_in, const int* in_sizes, int n_in,
                              void* d_out, int out_size, void* d_ws, size_t ws_size,
                              hipStream_t stream) {
  const void* x  = d_in[0];
  const void* ei = d_in[1];
  const void* W1 = d_in[2];
  const void* b1 = d_in[3];
  const void* W2 = d_in[4];
  const void* b2 = d_in[5];
  const int n = in_sizes[0] / IN_F;
  const int e = in_sizes[1] / 2;
  const int nb = (n + BINW - 1) / BINW;

  char* p = (char*)d_ws;
  auto alloc = [&](size_t bytes) -> char* {
    char* r = p;
    p += (bytes + 255) & ~(size_t)255;
    return r;
  };
  int*            flags  = (int*)alloc(256);
  unsigned*       gcnt   = (unsigned*)alloc(MAXNB * 4);
  unsigned*       offs   = (unsigned*)alloc(MAXNB * 4);
  unsigned*       gcur   = (unsigned*)alloc(MAXNB * 4);
  float*          dinv   = (float*)alloc((size_t)n * 4);
  unsigned*       offs2  = (unsigned*)alloc(((size_t)n + 1) * 4);
  unsigned short* hs1    = (unsigned short*)alloc((size_t)n * HID * 2);  // bf16 [n][16]
  unsigned short* hd     = (unsigned short*)alloc((size_t)n * HID * 2);  // bf16 [n][16]
  unsigned*       binbuf = (unsigned*)alloc((size_t)e * 4);
  unsigned*       csr    = (unsigned*)alloc((size_t)e * 4);

  const int nbE  = (e + 256 * EPT  - 1) / (256 * EPT);
  const int nbES = (e + 256 * EPTS - 1) / (256 * EPTS);
  const int nbW  = (n + 15) / 16;   // agg kernels: 4 waves/block x 4 nodes/wave

  k_detect<<<1, 256, 0, stream>>>(x, ei, flags);
  hipMemsetAsync(gcnt, 0, MAXNB * 4, stream);
  k_bincount<<<nbE, 256, 0, stream>>>(ei, flags, gcnt, e, nb);
  k_scan<<<1, 256, 0, stream>>>(gcnt, offs, gcur, nb);
  k_scatter<<<nbES, 256, 0, stream>>>(ei, flags, gcur, binbuf, e, nb);
  k_sort<<<nb, 512, 0, stream>>>(binbuf, offs, gcnt, csr, offs2, dinv, n, e);
  k_xw1<<<(n + 15) / 16, 256, 0, stream>>>(x, W1, flags, dinv, hs1, n);
  k_agg1<<<nbW, 256, 0, stream>>>(csr, offs2, dinv, (const uint4*)hs1, b1, flags,
                                  (uint4*)hd, n);
  k_agg2<<<nbW, 256, 0, stream>>>(csr, offs2, dinv, (const uint4*)hd, W2, b2, flags,
                                  d_out, n);
}

// Round 10
// 215.114 us; speedup vs baseline: 1.6593x; 1.0457x over previous
//
#include <hip/hip_runtime.h>
#include <hip/hip_bf16.h>

#define IN_F 128
#define HID 16
#define OUT_F 64
#define XT_LD 132   // padded LDS stride for x tile in k_xw1
#define BINW 512    // nodes per bin (dst >> 9)
#define BSH 9
#define MAXNB 256   // supports n <= 131072
#define EPT 16      // edges per thread in bincount
#define EPTS 16     // edges per thread in scatter

// ---------- dtype-flex helpers (device-side runtime dtype detection) ----------
__device__ __forceinline__ float loadF(const void* p, size_t i, int bf) {
  if (bf) {
    unsigned v = ((unsigned)((const unsigned short*)p)[i]) << 16;
    float f; __builtin_memcpy(&f, &v, 4); return f;
  }
  return ((const float*)p)[i];
}
__device__ __forceinline__ int loadE_nt(const void* p, size_t i, int i64) {
  if (i64) return __builtin_nontemporal_load((const int*)p + 2 * i);  // little-endian low word
  return __builtin_nontemporal_load((const int*)p + i);
}
// bf16 pack/unpack (RNE, matches __float2bfloat16)
__device__ __forceinline__ unsigned short f2bf(float f) {
  unsigned u; __builtin_memcpy(&u, &f, 4);
  return (unsigned short)((u + 0x7FFFu + ((u >> 16) & 1u)) >> 16);
}
// unpack uint4 (8 bf16) -> 8 f32, accumulate
__device__ __forceinline__ void acc8(const uint4 v, float* a) {
  const unsigned u[4] = {v.x, v.y, v.z, v.w};
  #pragma unroll
  for (int j = 0; j < 4; ++j) {
    unsigned lo = u[j] << 16, hi = u[j] & 0xFFFF0000u;
    float fl, fh; __builtin_memcpy(&fl, &lo, 4); __builtin_memcpy(&fh, &hi, 4);
    a[2 * j] += fl; a[2 * j + 1] += fh;
  }
}
__device__ __forceinline__ void unp8(const uint4 v, float* a) {
  const unsigned u[4] = {v.x, v.y, v.z, v.w};
  #pragma unroll
  for (int j = 0; j < 4; ++j) {
    unsigned lo = u[j] << 16, hi = u[j] & 0xFFFF0000u;
    __builtin_memcpy(&a[2 * j], &lo, 4); __builtin_memcpy(&a[2 * j + 1], &hi, 4);
  }
}
__device__ __forceinline__ uint4 pk8(const float* r) {
  uint4 o;
  o.x = (unsigned)f2bf(r[0]) | ((unsigned)f2bf(r[1]) << 16);
  o.y = (unsigned)f2bf(r[2]) | ((unsigned)f2bf(r[3]) << 16);
  o.z = (unsigned)f2bf(r[4]) | ((unsigned)f2bf(r[5]) << 16);
  o.w = (unsigned)f2bf(r[6]) | ((unsigned)f2bf(r[7]) << 16);
  return o;
}

// flags[0] = 1 if float tensors are bf16; flags[1] = 1 if edge_index is int64
__global__ void k_detect(const void* x, const void* ei, int* flags) {
  __shared__ int c_ok, c_hi;
  int t = threadIdx.x;
  if (t == 0) { c_ok = 0; c_hi = 0; }
  __syncthreads();
  const float* xf = (const float*)x;
  int ok = 0;
  for (int i = t; i < 1024; i += 256) {
    float v = fabsf(xf[i]);
    if (v > 1e-4f && v < 1e4f) ok++;
  }
  const int* ep = (const int*)ei;
  int hi = 0;
  for (int i = t; i < 1024; i += 256)
    if (ep[2 * i + 1] != 0) hi++;
  atomicAdd(&c_ok, ok);
  atomicAdd(&c_hi, hi);
  __syncthreads();
  if (t == 0) {
    flags[0] = (c_ok < 512) ? 1 : 0;
    flags[1] = (c_hi == 0) ? 1 : 0;
  }
}

// ---------- pass 1: per-bin edge counts ----------
__global__ __launch_bounds__(256) void k_bincount(const void* ei, const int* flags,
                                                  unsigned* gcnt, int e, int nb) {
  __shared__ unsigned hist[MAXNB];
  const int t = threadIdx.x;
  for (int i = t; i < nb; i += 256) hist[i] = 0;
  __syncthreads();
  const int i64 = flags[1];
  const size_t base = (size_t)blockIdx.x * (256 * EPT);
  #pragma unroll
  for (int j = 0; j < EPT; ++j) {
    size_t idx = base + (size_t)j * 256 + t;
    if (idx < (size_t)e) {
      int d = loadE_nt(ei, (size_t)e + idx, i64);
      atomicAdd(&hist[d >> BSH], 1u);
    }
  }
  __syncthreads();
  for (int i = t; i < nb; i += 256)
    if (hist[i]) atomicAdd(&gcnt[i], hist[i]);
}

// ---------- exclusive scan over bin counts ----------
__global__ __launch_bounds__(256) void k_scan(const unsigned* gcnt, unsigned* offs,
                                              unsigned* gcur, int nb) {
  __shared__ unsigned s[256];
  const int t = threadIdx.x;
  unsigned c[4]; unsigned sum = 0;
  #pragma unroll
  for (int j = 0; j < 4; ++j) {
    int i = t * 4 + j;
    c[j] = (i < nb) ? gcnt[i] : 0u;
    sum += c[j];
  }
  s[t] = sum; __syncthreads();
  for (int d = 1; d < 256; d <<= 1) {
    unsigned a = (t >= d) ? s[t - d] : 0u;
    __syncthreads();
    s[t] += a;
    __syncthreads();
  }
  unsigned run = s[t] - sum;
  #pragma unroll
  for (int j = 0; j < 4; ++j) {
    int i = t * 4 + j;
    if (i < nb) { offs[i] = run; gcur[i] = run; run += c[j]; }
  }
}

// ---------- pass 2: scatter edges into bins (wg-bulk reservation, PLAIN stores) ----------
__global__ __launch_bounds__(256) void k_scatter(const void* ei, const int* flags,
                                                 unsigned* gcur, unsigned* binbuf,
                                                 int e, int nb) {
  __shared__ unsigned hist[MAXNB];
  __shared__ unsigned rbase[MAXNB];
  const int t = threadIdx.x;
  for (int i = t; i < nb; i += 256) hist[i] = 0;
  __syncthreads();
  const int i64 = flags[1];
  const size_t base = (size_t)blockIdx.x * (256 * EPTS);
  unsigned pk[EPTS]; int bn[EPTS];
  #pragma unroll
  for (int j = 0; j < EPTS; ++j) {
    size_t idx = base + (size_t)j * 256 + t;
    if (idx < (size_t)e) {
      int s = loadE_nt(ei, idx, i64);
      int d = loadE_nt(ei, (size_t)e + idx, i64);
      bn[j] = d >> BSH;
      pk[j] = (unsigned)s | ((unsigned)(d & (BINW - 1)) << 17);
      atomicAdd(&hist[bn[j]], 1u);
    } else bn[j] = -1;
  }
  __syncthreads();
  for (int i = t; i < nb; i += 256) {
    unsigned h = hist[i];
    rbase[i] = h ? atomicAdd(&gcur[i], h) : 0u;
    hist[i] = 0;
  }
  __syncthreads();
  #pragma unroll
  for (int j = 0; j < EPTS; ++j)
    if (bn[j] >= 0) {
      unsigned p = rbase[bn[j]] + atomicAdd(&hist[bn[j]], 1u);
      binbuf[p] = pk[j];
    }
}

// ---------- pass 3: within-bin counting sort -> per-node CSR + dinv ----------
__global__ __launch_bounds__(512) void k_sort(const unsigned* binbuf, const unsigned* offs,
                                              const unsigned* gcnt, unsigned* csr,
                                              unsigned* offs2, float* dinv, int n, int e) {
  __shared__ unsigned hist[BINW];
  __shared__ unsigned scn[BINW];
  __shared__ unsigned cur[BINW];
  const int b = blockIdx.x, t = threadIdx.x;
  hist[t] = 0;
  __syncthreads();
  const unsigned off = offs[b], cnt = gcnt[b];
  for (unsigned i = t; i < cnt; i += 512)
    atomicAdd(&hist[binbuf[off + i] >> 17], 1u);
  __syncthreads();
  scn[t] = hist[t];
  __syncthreads();
  for (int d = 1; d < BINW; d <<= 1) {
    unsigned a = (t >= d) ? scn[t - d] : 0u;
    __syncthreads();
    scn[t] += a;
    __syncthreads();
  }
  {
    unsigned excl = scn[t] - hist[t];
    cur[t] = excl;
    int g = b * BINW + t;
    if (g < n) {
      offs2[g] = off + excl;
      dinv[g] = rsqrtf((float)(hist[t] + 1u));   // +1 self-loop
    }
  }
  if (b == 0 && t == 0) offs2[n] = (unsigned)e;
  __syncthreads();
  for (unsigned i = t; i < cnt; i += 512) {
    unsigned pk = binbuf[off + i];
    unsigned dl = pk >> 17;
    unsigned p = atomicAdd(&cur[dl], 1u);
    csr[off + p] = pk & 0x1FFFFu;
  }
}

// ---------- hs1 = bf16( dinv[n] * (x @ W1) ), [n][16] bf16 (3.2MB, L2-resident) ----------
__global__ __launch_bounds__(256) void k_xw1(const void* x, const void* W1,
                                             const int* flags, const float* dinv,
                                             unsigned short* hs1, int n) {
  __shared__ float w[IN_F * HID];
  __shared__ float xt[16 * XT_LD];
  const int t = threadIdx.x;
  const int bf = flags[0];
  for (int i = t; i < IN_F * HID; i += 256) w[i] = loadF(W1, i, bf);
  const int n0 = blockIdx.x * 16;
  if (!bf) {
    const float4* xv = (const float4*)x;
    for (int i = t; i < 16 * (IN_F / 4); i += 256) {
      int rl = i >> 5, k4 = i & 31;
      int row = n0 + rl;
      float4 v = (row < n) ? xv[(size_t)row * 32 + k4]
                           : make_float4(0.f, 0.f, 0.f, 0.f);
      float* xp = xt + rl * XT_LD + k4 * 4;
      xp[0] = v.x; xp[1] = v.y; xp[2] = v.z; xp[3] = v.w;
    }
  } else {
    for (int i = t; i < 16 * IN_F; i += 256) {
      int rl = i >> 7, k = i & 127;
      int row = n0 + rl;
      xt[rl * XT_LD + k] = (row < n) ? loadF(x, (size_t)row * IN_F + k, bf) : 0.f;
    }
  }
  __syncthreads();
  const int ln = t >> 4, c = t & 15;
  const int node = n0 + ln;
  if (node >= n) return;
  float acc = 0.f;
  #pragma unroll 16
  for (int k = 0; k < IN_F; ++k)
    acc = fmaf(xt[ln * XT_LD + k], w[k * HID + c], acc);
  hs1[(size_t)node * HID + c] = f2bf(dinv[node] * acc);
}

// ---------- layer-1 aggregation: 4 nodes/wave (16 lanes/node), bf16 gather ----------
// lane16 = lane&15; sub = lane16>>1 (8 edge slots), q = lane16&1 (16B half of row)
// 2-deep unrolled gather; csr reads are NONTEMPORAL (rounds 4-8 pass history —
// plain cached csr reads diverged under graph replay in round 9).
__global__ __launch_bounds__(256) void k_agg1(const unsigned* csr, const unsigned* offs2,
                                              const float* dinv, const uint4* tbl,
                                              const void* b1, const int* flags,
                                              uint4* hd, int n) {
  const int wave = (blockIdx.x * 256 + threadIdx.x) >> 6;
  const int lane = threadIdx.x & 63;
  const int g = lane >> 4, lane16 = lane & 15;
  const int node = wave * 4 + g;
  if (node >= n) return;
  const int sub = lane16 >> 1, q = lane16 & 1;
  const unsigned off = offs2[node];
  const unsigned cnt = offs2[node + 1] - off;
  // independent loads issued early
  const float di = dinv[node];
  const uint4 selfv = tbl[(size_t)node * 2 + q];
  float a[8] = {0, 0, 0, 0, 0, 0, 0, 0};
  unsigned i = sub;
  while (i + 8 < cnt) {
    unsigned s0 = __builtin_nontemporal_load(csr + off + i);
    unsigned s1 = __builtin_nontemporal_load(csr + off + i + 8);
    uint4 v0 = tbl[(size_t)s0 * 2 + q];
    uint4 v1 = tbl[(size_t)s1 * 2 + q];
    acc8(v0, a); acc8(v1, a);
    i += 16;
  }
  if (i < cnt) {
    unsigned s = __builtin_nontemporal_load(csr + off + i);
    acc8(tbl[(size_t)s * 2 + q], a);
  }
  #pragma unroll
  for (int m = 2; m < 16; m <<= 1) {
    #pragma unroll
    for (int j = 0; j < 8; ++j) a[j] += __shfl_xor(a[j], m, 64);
  }
  if (lane16 < 2) {
    float sv[8]; unp8(selfv, sv);
    const int bf = flags[0];
    float r[8];
    #pragma unroll
    for (int j = 0; j < 8; ++j)
      r[j] = di * fmaxf(fmaf(di, a[j] + sv[j], loadF(b1, q * 8 + j, bf)), 0.f);
    hd[(size_t)node * 2 + q] = pk8(r);
  }
}

// ---------- layer-2 aggregation + fused 16->64 transform + relu, 4 nodes/wave ----------
__global__ __launch_bounds__(256) void k_agg2(const unsigned* csr, const unsigned* offs2,
                                              const float* dinv, const uint4* tbl,
                                              const void* W2, const void* b2,
                                              const int* flags, void* out, int n) {
  __shared__ float w2s[HID * OUT_F];
  const int t = threadIdx.x;
  const int bf = flags[0];
  for (int i = t; i < HID * OUT_F; i += 256) w2s[i] = loadF(W2, i, bf);
  __syncthreads();
  const int wave = (blockIdx.x * 256 + t) >> 6;
  const int lane = t & 63;
  const int g = lane >> 4, lane16 = lane & 15;
  const int node = wave * 4 + g;
  if (node >= n) return;
  const int sub = lane16 >> 1, q = lane16 & 1;
  const unsigned off = offs2[node];
  const unsigned cnt = offs2[node + 1] - off;
  const float di = dinv[node];
  const uint4 selfv = tbl[(size_t)node * 2 + q];
  float a[8] = {0, 0, 0, 0, 0, 0, 0, 0};
  unsigned i = sub;
  while (i + 8 < cnt) {
    unsigned s0 = __builtin_nontemporal_load(csr + off + i);
    unsigned s1 = __builtin_nontemporal_load(csr + off + i + 8);
    uint4 v0 = tbl[(size_t)s0 * 2 + q];
    uint4 v1 = tbl[(size_t)s1 * 2 + q];
    acc8(v0, a); acc8(v1, a);
    i += 16;
  }
  if (i < cnt) {
    unsigned s = __builtin_nontemporal_load(csr + off + i);
    acc8(tbl[(size_t)s * 2 + q], a);
  }
  #pragma unroll
  for (int m = 2; m < 16; m <<= 1) {
    #pragma unroll
    for (int j = 0; j < 8; ++j) a[j] += __shfl_xor(a[j], m, 64);
  }
  // every lane now holds its parity's total; z = dinv*(acc+self)
  float sv[8]; unp8(selfv, sv);
  float zk[16];
  #pragma unroll
  for (int j = 0; j < 8; ++j) {
    float r = di * (a[j] + sv[j]);
    zk[q * 8 + j] = r;
    zk[(1 - q) * 8 + j] = __shfl_xor(r, 1, 64);   // grab the other parity's channels
  }
  // each lane computes 4 of the 64 outputs: o = lane16*4 + jj
  const int ob = lane16 * 4;
  float o0 = loadF(b2, ob + 0, bf), o1 = loadF(b2, ob + 1, bf);
  float o2 = loadF(b2, ob + 2, bf), o3 = loadF(b2, ob + 3, bf);
  #pragma unroll
  for (int k = 0; k < HID; ++k) {
    const float* wr = w2s + k * OUT_F + ob;
    o0 = fmaf(zk[k], wr[0], o0);
    o1 = fmaf(zk[k], wr[1], o1);
    o2 = fmaf(zk[k], wr[2], o2);
    o3 = fmaf(zk[k], wr[3], o3);
  }
  o0 = fmaxf(o0, 0.f); o1 = fmaxf(o1, 0.f);
  o2 = fmaxf(o2, 0.f); o3 = fmaxf(o3, 0.f);
  const size_t oi = (size_t)node * OUT_F + ob;
  if (bf) {
    __hip_bfloat16* op = (__hip_bfloat16*)out + oi;
    op[0] = __float2bfloat16(o0); op[1] = __float2bfloat16(o1);
    op[2] = __float2bfloat16(o2); op[3] = __float2bfloat16(o3);
  } else {
    float4 v = make_float4(o0, o1, o2, o3);
    *(float4*)((float*)out + oi) = v;
  }
}

extern "C" void kernel_launch(void* const* d_in, const int* in_sizes, int n_in,
                              void* d_out, int out_size, void* d_ws, size_t ws_size,
                              hipStream_t stream) {
  const void* x  = d_in[0];
  const void* ei = d_in[1];
  const void* W1 = d_in[2];
  const void* b1 = d_in[3];
  const void* W2 = d_in[4];
  const void* b2 = d_in[5];
  const int n = in_sizes[0] / IN_F;
  const int e = in_sizes[1] / 2;
  const int nb = (n + BINW - 1) / BINW;

  char* p = (char*)d_ws;
  auto alloc = [&](size_t bytes) -> char* {
    char* r = p;
    p += (bytes + 255) & ~(size_t)255;
    return r;
  };
  int*            flags  = (int*)alloc(256);
  unsigned*       gcnt   = (unsigned*)alloc(MAXNB * 4);
  unsigned*       offs   = (unsigned*)alloc(MAXNB * 4);
  unsigned*       gcur   = (unsigned*)alloc(MAXNB * 4);
  float*          dinv   = (float*)alloc((size_t)n * 4);
  unsigned*       offs2  = (unsigned*)alloc(((size_t)n + 1) * 4);
  unsigned short* hs1    = (unsigned short*)alloc((size_t)n * HID * 2);  // bf16 [n][16]
  unsigned short* hd     = (unsigned short*)alloc((size_t)n * HID * 2);  // bf16 [n][16]
  unsigned*       binbuf = (unsigned*)alloc((size_t)e * 4);
  unsigned*       csr    = (unsigned*)alloc((size_t)e * 4);

  const int nbE  = (e + 256 * EPT  - 1) / (256 * EPT);
  const int nbES = (e + 256 * EPTS - 1) / (256 * EPTS);
  const int nbW  = (n + 15) / 16;   // agg kernels: 4 waves/block x 4 nodes/wave

  k_detect<<<1, 256, 0, stream>>>(x, ei, flags);
  hipMemsetAsync(gcnt, 0, MAXNB * 4, stream);
  k_bincount<<<nbE, 256, 0, stream>>>(ei, flags, gcnt, e, nb);
  k_scan<<<1, 256, 0, stream>>>(gcnt, offs, gcur, nb);
  k_scatter<<<nbES, 256, 0, stream>>>(ei, flags, gcur, binbuf, e, nb);
  k_sort<<<nb, 512, 0, stream>>>(binbuf, offs, gcnt, csr, offs2, dinv, n, e);
  k_xw1<<<(n + 15) / 16, 256, 0, stream>>>(x, W1, flags, dinv, hs1, n);
  k_agg1<<<nbW, 256, 0, stream>>>(csr, offs2, dinv, (const uint4*)hs1, b1, flags,
                                  (uint4*)hd, n);
  k_agg2<<<nbW, 256, 0, stream>>>(csr, offs2, dinv, (const uint4*)hd, W2, b2, flags,
                                  d_out, n);
}